// Round 13
// baseline (792.976 us; speedup 1.0000x reference)
//
#include <hip/hip_runtime.h>
#include <hip/hip_bf16.h>
#include <stdint.h>

#define SEQLEN 512
#define NBATCH 64
#define KDIM   512
#define HDIM   1024
#define MTOT   (SEQLEN * NBATCH)   // 32768
#define NTOT   (3 * HDIM)          // 3072
#define STRIDE (NBATCH * HDIM)     // 65536

typedef __attribute__((ext_vector_type(4))) float f32x4;
typedef _Float16 f16x8 __attribute__((ext_vector_type(8)));

// ---------- merged conversion ------------------------------------------
// hi planes: linear [row][k] (staged to LDS in GEMM).
// lo planes: FRAGMENT-MAJOR [tile16][ktile][lane]x8elems — GEMM loads lo
// fragments directly global->VGPR, one coalesced dwordx4 per wave per frag.
// 3-pass MFMA (AhBh+AhBl+AlBh) ~= fp32 GEMM (r5: 2-pass fails at 0.51).
#define XTHREADS (MTOT * KDIM / 8)   // 2,097,152
#define UTHREADS (NTOT * KDIM / 8)   //   196,608
#define KT_N (KDIM / 32)             // 16

__global__ __launch_bounds__(256) void cvt_all(const float* __restrict__ x,
                                               const float* __restrict__ Uc,
                                               const float* __restrict__ Ua,
                                               const float* __restrict__ Uh,
                                               _Float16* __restrict__ xh,
                                               _Float16* __restrict__ xlf,
                                               _Float16* __restrict__ uh,
                                               _Float16* __restrict__ ulf) {
    int i = blockIdx.x * 256 + threadIdx.x;
    const float* src;
    _Float16 *dh, *dlf;
    int row, kb;
    if (i < XTHREADS) {
        row = i >> 6; kb = (i & 63) * 8;
        src = x + (size_t)i * 8;
        dh = xh; dlf = xlf;
    } else {
        int u = i - XTHREADS;
        row = u >> 6; kb = (u & 63) * 8;
        src = ((row < HDIM) ? (Uc + (size_t)row * KDIM)
             : (row < 2 * HDIM) ? (Ua + (size_t)(row - HDIM) * KDIM)
             : (Uh + (size_t)(row - 2 * HDIM) * KDIM)) + kb;
        dh = uh; dlf = ulf;
    }
    const float4* s = (const float4*)src;
    float4 a = s[0], b = s[1];
    float v[8] = {a.x, a.y, a.z, a.w, b.x, b.y, b.z, b.w};
    f16x8 hi, lo;
#pragma unroll
    for (int j = 0; j < 8; ++j) {
        _Float16 h = (_Float16)v[j];
        hi[j] = h;
        lo[j] = (_Float16)(v[j] - (float)h);
    }
    *(f16x8*)(dh + (size_t)row * KDIM + kb) = hi;
    // fragment-major lo: tile16=row>>4, ktile=kb>>5, chunk=(kb>>3)&3,
    // lane=(row&15)+16*chunk; elem addr = (tile16*KT_N+ktile)*512 + lane*8
    int lane16 = (row & 15) + (((kb >> 3) & 3) << 4);
    size_t lof = ((size_t)((row >> 4) * KT_N + (kb >> 5))) * 512 + lane16 * 8;
    *(f16x8*)(dlf + lof) = lo;
}

// --------- GEMM: proj[M][3072] = (Xh+Xl)·(Uh+Ul)^T, 3-pass split ---------
// Round-13: LDS carries ONLY hi planes (32 KB/tile, 12 reads/wave); lo
// fragments stream global->VGPR from the fragment-major layout (12 coalesced
// dwordx4 per wave, double-buffered register sets, consumed NEXT body — the
// boundary vmcnt(0) already guarantees arrival; no new waits).
// Cycle model: r6 serialized LDS(2800)+MFMA(3725)=7030 cyc/tile (measured);
// this cuts LDS content to ~1400 -> ~5600 cyc/tile ceiling.
// Schedule = r6 relaxed (best of 5 tried): one raw barrier + vmcnt(0)/tile.
#define BM 256
#define BN 256
#define BK 32
#define NT_N (NTOT / BN)            // 12
#define GRID ((MTOT / BM) * NT_N)   // 1536
// LDS: hi planes only. [buf][A 256*32 | B 256*32] halfwords = 32 KB/buf.
#define OFF_AH 0
#define OFF_BH 8192
#define BUF_HW 16384

__device__ __forceinline__ void gload16(const _Float16* g, _Float16* l) {
    __builtin_amdgcn_global_load_lds((const __attribute__((address_space(1))) void*)g,
                                     (__attribute__((address_space(3))) void*)l,
                                     16, 0, 0);
}

__device__ __forceinline__ f32x4 mfma16(f16x8 a, f16x8 b, f32x4 c) {
    return __builtin_amdgcn_mfma_f32_16x16x32_f16(a, b, c, 0, 0, 0);
}

__global__ __launch_bounds__(512, 2) void gemm_f16x2(const _Float16* __restrict__ Ah,
                                                     const _Float16* __restrict__ Alo,
                                                     const _Float16* __restrict__ Bh,
                                                     const _Float16* __restrict__ Blo,
                                                     float* __restrict__ pc,
                                                     float* __restrict__ pa,
                                                     float* __restrict__ ph) {
    __shared__ _Float16 lds[2][BUF_HW];   // 64 KB total

    int bid  = blockIdx.x;          // default order, A-panel-major
    int bm   = bid / NT_N;
    int bn   = bid % NT_N;
    int tid  = threadIdx.x;
    int lane = tid & 63;
    int wave = tid >> 6;
    int wr   = wave >> 2;           // 0..1 (M half, 128 rows)
    int wc   = wave & 3;            // 0..3 (N quarter, 64 cols)

    // hi staging (T2 source-side chunk permute; conflict-free r3-r7)
    size_t row_off = (size_t)(tid >> 2) * KDIM
                   + (size_t)(((tid & 3) ^ ((tid >> 3) & 3)) * 8);
    const _Float16* gAh = Ah + (size_t)bm * BM * KDIM + row_off;
    const _Float16* gBh = Bh + (size_t)bn * BN * KDIM + row_off;
    const size_t P128 = (size_t)128 * KDIM;   // +128 rows in global
    int t8 = tid * 8;

#define STAGE_A(buf, kt) do { int _g = (kt) * BK;                              \
    gload16(gAh + _g,        &lds[buf][OFF_AH + t8]);                          \
    gload16(gAh + P128 + _g, &lds[buf][OFF_AH + 4096 + t8]); } while (0)
#define STAGE_B(buf, kt) do { int _g = (kt) * BK;                              \
    gload16(gBh + _g,        &lds[buf][OFF_BH + t8]);                          \
    gload16(gBh + P128 + _g, &lds[buf][OFF_BH + 4096 + t8]); } while (0)

    // lo fragment bases: frag (tile16, kt) at (tile16*KT_N+kt)*512 + lane*8
    const _Float16* aloB = Alo + (size_t)(bm * 16 + wr * 8) * KT_N * 512 + lane * 8;
    const _Float16* bloB = Blo + (size_t)(bn * 16 + wc * 4) * KT_N * 512 + lane * 8;

#define LOAD_LO(aS, bS, kt) do { _Pragma("unroll")                             \
    for (int i = 0; i < 8; ++i)                                                \
        aS[i] = *(const f16x8*)(aloB + ((size_t)i * KT_N + (kt)) * 512);       \
    _Pragma("unroll")                                                          \
    for (int j = 0; j < 4; ++j)                                                \
        bS[j] = *(const f16x8*)(bloB + ((size_t)j * KT_N + (kt)) * 512);       \
    } while (0)

    f32x4 acc[8][4];
#pragma unroll
    for (int i = 0; i < 8; ++i)
#pragma unroll
        for (int j = 0; j < 4; ++j)
            acc[i][j] = (f32x4){0.f, 0.f, 0.f, 0.f};

    int ro = lane & 15;
    int ko = ((lane >> 4) ^ ((lane >> 1) & 3)) * 8;   // read-side swizzle

    f16x8 a0_[4], a1_[4], bh_[4];             // hi frags (LDS, same-body)
    f16x8 aloX[8], bloX[4], aloY[8], bloY[4]; // lo frags (global, next-body)

#define READ_A(arr, mh, cb) _Pragma("unroll")                                  \
    for (int i = 0; i < 4; ++i) {                                              \
        int row = wr * 128 + ((mh) * 4 + i) * 16 + ro;                         \
        arr[i] = *(const f16x8*)(&lds[cb][OFF_AH + row * BK + ko]);            \
    }
#define READ_B(cb) _Pragma("unroll")                                           \
    for (int j = 0; j < 4; ++j) {                                              \
        int row = wc * 64 + j * 16 + ro;                                       \
        bh_[j] = *(const f16x8*)(&lds[cb][OFF_BH + row * BK + ko]);            \
    }
// pass order per acc unchanged from r6 -> bit-identical numerics
#define MFMA_HALF(mh, aHi, aLo, bLo) _Pragma("unroll")                         \
    for (int i = 0; i < 4; ++i) _Pragma("unroll")                              \
        for (int j = 0; j < 4; ++j) {                                          \
            f32x4 c = acc[(mh) * 4 + i][j];                                    \
            c = mfma16(aHi[i], bLo[j], c);            /* Ah·Bl */              \
            c = mfma16(aLo[(mh) * 4 + i], bh_[j], c); /* Al·Bh */              \
            c = mfma16(aHi[i], bh_[j], c);            /* Ah·Bh */              \
            acc[(mh) * 4 + i][j] = c;                                          \
        }

#define BODY(kt, LOA, LOB, NXA, NXB) do {                                      \
    int cur = (kt) & 1, nxt = 1 - cur;                                         \
    bool pre = ((kt) < KT_N - 1);                                              \
    __builtin_amdgcn_sched_barrier(0);                                         \
    asm volatile("s_waitcnt vmcnt(0)" ::: "memory");                           \
    __builtin_amdgcn_s_barrier();                                              \
    __builtin_amdgcn_sched_barrier(0);                                         \
    if (pre) LOAD_LO(NXA, NXB, (kt) + 1);   /* for next body, no consumer */   \
    READ_B(cur);                                                               \
    READ_A(a0_, 0, cur);                                                       \
    if (pre) STAGE_A(nxt, (kt) + 1);                                           \
    __builtin_amdgcn_s_setprio(1);                                             \
    MFMA_HALF(0, a0_, LOA, LOB);                                               \
    __builtin_amdgcn_s_setprio(0);                                             \
    READ_A(a1_, 1, cur);                                                       \
    if (pre) STAGE_B(nxt, (kt) + 1);                                           \
    __builtin_amdgcn_s_setprio(1);                                             \
    MFMA_HALF(1, a1_, LOA, LOB);                                               \
    __builtin_amdgcn_s_setprio(0);                                             \
} while (0)

    // prologue: hi tile 0 -> buf 0; lo tile 0 -> set X
    STAGE_A(0, 0); STAGE_B(0, 0);
    LOAD_LO(aloX, bloX, 0);

    for (int kt = 0; kt < KT_N; kt += 2) {
        BODY(kt,     aloX, bloX, aloY, bloY);
        BODY(kt + 1, aloY, bloY, aloX, bloX);
    }

    // epilogue: D col=lane&15 (N), row=(lane>>4)*4+r (M)  [m89-verified]
    // BN=256 divides HDIM -> whole block routes to one output buffer.
    int n0 = bn * BN;
    float* outp; int nb;
    if (n0 < HDIM)            { outp = pc; nb = n0; }
    else if (n0 < 2 * HDIM)   { outp = pa; nb = n0 - HDIM; }
    else                      { outp = ph; nb = n0 - 2 * HDIM; }

#pragma unroll
    for (int ai = 0; ai < 8; ++ai)
#pragma unroll
        for (int bj = 0; bj < 4; ++bj) {
            int m = bm * BM + wr * 128 + ai * 16 + (lane >> 4) * 4;
            int n = nb + wc * 64 + bj * 16 + (lane & 15);
#pragma unroll
            for (int r = 0; r < 4; ++r)
                outp[(size_t)(m + r) * HDIM + n] = acc[ai][bj][r];
        }
#undef STAGE_A
#undef STAGE_B
#undef LOAD_LO
#undef READ_A
#undef READ_B
#undef MFMA_HALF
#undef BODY
}

// ------------------------- recurrence ------------------------------------
// one thread per (b,j); 65536 threads; depth-16 register prefetch pipeline
// (PF=16: 48 outstanding loads <= 63 vmcnt capacity; PF=32 exceeded it).
// libm transcendentals (r8 measured: fast variants null — BW/latency-bound).
__global__ __launch_bounds__(256) void recur(const float* __restrict__ pc_a,
                                             const float* __restrict__ pa_a,
                                             float* out,
                                             const float* __restrict__ h0,
                                             const float* __restrict__ wc_,
                                             const float* __restrict__ bc_,
                                             const float* __restrict__ wa_,
                                             const float* __restrict__ ba_,
                                             const float* __restrict__ bh_) {
    int idx = blockIdx.x * 256 + threadIdx.x;
    int j = idx & (HDIM - 1);
    float h  = h0[idx];
    float wc = wc_[j], bc = bc_[j];
    float wa = wa_[j], ba = ba_[j];
    float bh = bh_[j];

#define PF 16
    float pc[PF], pa[PF], ph[PF];
#pragma unroll
    for (int u = 0; u < PF; ++u) {
        pc[u] = pc_a[(size_t)u * STRIDE + idx];
        pa[u] = pa_a[(size_t)u * STRIDE + idx];
        ph[u] = out [(size_t)u * STRIDE + idx];
    }

    for (int sb = 0; sb < SEQLEN; sb += PF) {
#pragma unroll
        for (int u = 0; u < PF; ++u) {
            int s = sb + u;
            float vc = pc[u], va = pa[u], vh = ph[u];
            int sp = s + PF; sp = (sp < SEQLEN) ? sp : (SEQLEN - 1);
            pc[u] = pc_a[(size_t)sp * STRIDE + idx];
            pa[u] = pa_a[(size_t)sp * STRIDE + idx];
            ph[u] = out [(size_t)sp * STRIDE + idx];

            float zc = (vc + bc) + wc * h;
            float za = (va + ba) + wa * h;
            float c  = 1.0f / (1.0f + expf(-zc));
            float a  = 1.0f + tanhf(za);
            float ht = tanhf((vh + bh) + a * h);
            h = c * h + (1.0f - c) * ht;
            out[(size_t)s * STRIDE + idx] = h;
        }
    }
    out[(size_t)SEQLEN * STRIDE + idx] = h;   // hn
}

// --------------------------- launch --------------------------------------
extern "C" void kernel_launch(void* const* d_in, const int* in_sizes, int n_in,
                              void* d_out, int out_size, void* d_ws, size_t ws_size,
                              hipStream_t stream) {
    const float* x_seq = (const float*)d_in[0];
    const float* h0    = (const float*)d_in[1];
    const float* U_c   = (const float*)d_in[2];
    const float* w_c   = (const float*)d_in[3];
    const float* b_c   = (const float*)d_in[4];
    const float* U_a   = (const float*)d_in[5];
    const float* w_a   = (const float*)d_in[6];
    const float* b_a   = (const float*)d_in[7];
    const float* U_h   = (const float*)d_in[8];
    const float* b_h   = (const float*)d_in[9];
    float* out = (float*)d_out;

    char* ws = (char*)d_ws;
    const size_t MB = 1024 * 1024;
    float*    ws_pc = (float*)ws;                        // 128 MB
    float*    ws_pa = (float*)(ws + 128 * MB);           // 128 MB
    _Float16* x_hi  = (_Float16*)(ws + 256 * MB);        // 32 MB linear
    _Float16* x_lof = (_Float16*)(ws + 288 * MB);        // 32 MB frag-major
    _Float16* u_hi  = (_Float16*)(ws + 320 * MB);        // 3 MB linear
    _Float16* u_lof = (_Float16*)(ws + 323 * MB);        // 3 MB frag-major

    cvt_all<<<dim3((XTHREADS + UTHREADS) / 256), dim3(256), 0, stream>>>(
        x_seq, U_c, U_a, U_h, x_hi, x_lof, u_hi, u_lof);
    gemm_f16x2<<<dim3(GRID), dim3(512), 0, stream>>>(
        x_hi, x_lof, u_hi, u_lof, ws_pc, ws_pa, out);
    recur<<<dim3(STRIDE / 256), dim3(256), 0, stream>>>(ws_pc, ws_pa, out, h0,
                                                        w_c, b_c, w_a, b_a, b_h);
}

// Round 14
// 520.961 us; speedup vs baseline: 1.5221x; 1.5221x over previous
//
#include <hip/hip_runtime.h>
#include <hip/hip_bf16.h>
#include <stdint.h>

#define SEQLEN 512
#define NBATCH 64
#define KDIM   512
#define HDIM   1024
#define MTOT   (SEQLEN * NBATCH)   // 32768
#define NTOT   (3 * HDIM)          // 3072
#define STRIDE (NBATCH * HDIM)     // 65536

typedef __attribute__((ext_vector_type(4))) float f32x4;
typedef _Float16 f16x8 __attribute__((ext_vector_type(8)));

// ---------- merged conversion: x and U -> (hi, lo) fp16 planes -----------
// 3-pass MFMA (AhBh+AhBl+AlBh) ~= fp32 GEMM (r5: 2-pass fails at 0.51).
#define XTHREADS (MTOT * KDIM / 8)   // 2,097,152
#define UTHREADS (NTOT * KDIM / 8)   //   196,608
__global__ __launch_bounds__(256) void cvt_all(const float* __restrict__ x,
                                               const float* __restrict__ Uc,
                                               const float* __restrict__ Ua,
                                               const float* __restrict__ Uh,
                                               _Float16* __restrict__ xh,
                                               _Float16* __restrict__ xl,
                                               _Float16* __restrict__ uh,
                                               _Float16* __restrict__ ul) {
    int i = blockIdx.x * 256 + threadIdx.x;
    const float* src;
    _Float16 *dh, *dl;
    size_t off;
    if (i < XTHREADS) {
        src = x + (size_t)i * 8;
        off = (size_t)i * 8;
        dh = xh; dl = xl;
    } else {
        int u = i - XTHREADS;
        int n = u >> 6;
        int kb = (u & 63) * 8;
        src = ((n < HDIM) ? (Uc + (size_t)n * KDIM)
             : (n < 2 * HDIM) ? (Ua + (size_t)(n - HDIM) * KDIM)
             : (Uh + (size_t)(n - 2 * HDIM) * KDIM)) + kb;
        off = (size_t)n * KDIM + kb;
        dh = uh; dl = ul;
    }
    const float4* s = (const float4*)src;
    float4 a = s[0], b = s[1];
    float v[8] = {a.x, a.y, a.z, a.w, b.x, b.y, b.z, b.w};
    f16x8 hi, lo;
#pragma unroll
    for (int j = 0; j < 8; ++j) {
        _Float16 h = (_Float16)v[j];
        hi[j] = h;
        lo[j] = (_Float16)(v[j] - (float)h);
    }
    *(f16x8*)(dh + off) = hi;
    *(f16x8*)(dl + off) = lo;
}

// --------- GEMM: proj[M][3072] = (Xh+Xl)·(Uh+Ul)^T, 3-pass split ---------
// Round-14 = round-12 structure + PINNED read clusters.
// r12 post-mortem: compiler sank the next-tile ds_reads below the MFMAs to
// shrink live ranges (VGPR 108 reported vs ~210 declared) — the prefetch
// never existed in the emitted stream. Fix: sched_barrier(0) fences around
// {READF(kt+1)} and {STAGE(kt+2)} so the order reads->stage->MFMA is pinned.
// Then MFMA(kt) has no in-body operand waits (read a full body ago), the
// 16-read cluster retires under the 48-MFMA window, and vmcnt(0) at the
// boundary drains a stage issued a full body earlier.
#define BM 256
#define BN 128
#define BK 32
#define NT_N (NTOT / BN)            // 24
#define GRID ((MTOT / BM) * NT_N)   // 3072
#define KT_N (KDIM / BK)            // 16
// halfword offsets within one 48 KB buffer
#define OFF_AH 0
#define OFF_AL 8192
#define OFF_BH 16384
#define OFF_BL 20480
#define BUF_HW 24576

__device__ __forceinline__ void gload16(const _Float16* g, _Float16* l) {
    __builtin_amdgcn_global_load_lds((const __attribute__((address_space(1))) void*)g,
                                     (__attribute__((address_space(3))) void*)l,
                                     16, 0, 0);
}

__device__ __forceinline__ f32x4 mfma16(f16x8 a, f16x8 b, f32x4 c) {
    return __builtin_amdgcn_mfma_f32_16x16x32_f16(a, b, c, 0, 0, 0);
}

__global__ __launch_bounds__(512, 2) void gemm_f16x2(const _Float16* __restrict__ Ah,
                                                     const _Float16* __restrict__ Al,
                                                     const _Float16* __restrict__ Bh,
                                                     const _Float16* __restrict__ Bl,
                                                     float* __restrict__ pc,
                                                     float* __restrict__ pa,
                                                     float* __restrict__ ph) {
    __shared__ _Float16 lds[3][BUF_HW];   // 147456 B -> 1 block/CU

    int bid  = blockIdx.x;          // default order, A-panel-major
    int bm   = bid / NT_N;
    int bn   = bid % NT_N;
    int tid  = threadIdx.x;
    int lane = tid & 63;
    int wave = tid >> 6;
    int wr   = wave >> 1;           // 0..3 (M quarter, 64 rows)
    int wc   = wave & 1;            // 0..1 (N half, 64 cols)

    // staging (T2 source-side chunk permute; measured conflict-free r3-r12)
    size_t row_off = (size_t)(tid >> 2) * KDIM
                   + (size_t)(((tid & 3) ^ ((tid >> 3) & 3)) * 8);
    const _Float16* gAh = Ah + (size_t)bm * BM * KDIM + row_off;
    const _Float16* gAl = Al + (size_t)bm * BM * KDIM + row_off;
    const _Float16* gBh = Bh + (size_t)bn * BN * KDIM + row_off;
    const _Float16* gBl = Bl + (size_t)bn * BN * KDIM + row_off;
    const size_t P128 = (size_t)128 * KDIM;   // +128 rows in global
    int t8 = tid * 8;

// 6 loads/tile: A planes 2 each (256 rows), B planes 1 each (128 rows)
#define STAGE(buf, kt) do { int _g = (kt) * BK;                                \
    gload16(gAh + _g,        &lds[buf][OFF_AH + t8]);                          \
    gload16(gAh + P128 + _g, &lds[buf][OFF_AH + 4096 + t8]);                   \
    gload16(gAl + _g,        &lds[buf][OFF_AL + t8]);                          \
    gload16(gAl + P128 + _g, &lds[buf][OFF_AL + 4096 + t8]);                   \
    gload16(gBh + _g,        &lds[buf][OFF_BH + t8]);                          \
    gload16(gBl + _g,        &lds[buf][OFF_BL + t8]); } while (0)

    f32x4 acc[4][4];
#pragma unroll
    for (int i = 0; i < 4; ++i)
#pragma unroll
        for (int j = 0; j < 4; ++j)
            acc[i][j] = (f32x4){0.f, 0.f, 0.f, 0.f};

    int ro = lane & 15;
    int ko = ((lane >> 4) ^ ((lane >> 1) & 3)) * 8;   // read-side swizzle

    // two named fragment sets (rule #20: no runtime indexing)
    f16x8 aX[4][2], bX[4][2], aY[4][2], bY[4][2];

#define READF(aS, bS, cb) do { _Pragma("unroll")                               \
    for (int i = 0; i < 4; ++i) {                                              \
        int row = wr * 64 + i * 16 + ro;                                       \
        aS[i][0] = *(const f16x8*)(&lds[cb][OFF_AH + row * BK + ko]);          \
        aS[i][1] = *(const f16x8*)(&lds[cb][OFF_AL + row * BK + ko]);          \
    }                                                                          \
    _Pragma("unroll")                                                          \
    for (int j = 0; j < 4; ++j) {                                              \
        int row = wc * 64 + j * 16 + ro;                                       \
        bS[j][0] = *(const f16x8*)(&lds[cb][OFF_BH + row * BK + ko]);          \
        bS[j][1] = *(const f16x8*)(&lds[cb][OFF_BL + row * BK + ko]);          \
    } } while (0)

#define MFMAS(aS, bS) _Pragma("unroll")                                        \
    for (int i = 0; i < 4; ++i) _Pragma("unroll")                              \
        for (int j = 0; j < 4; ++j) {                                          \
            f32x4 c = acc[i][j];                                               \
            c = mfma16(aS[i][0], bS[j][1], c);   /* Ah·Bl */                   \
            c = mfma16(aS[i][1], bS[j][0], c);   /* Al·Bh */                   \
            c = mfma16(aS[i][0], bS[j][0], c);   /* Ah·Bh */                   \
            acc[i][j] = c;                                                     \
        }

#define FENCE __builtin_amdgcn_sched_barrier(0)

// body kt: boundary; PINNED {reads(kt+1)} then {stage(kt+2)} then MFMA(kt).
#define BODY(kt, ACUR, BCUR, ANXT, BNXT, cbn, cbt) do {                        \
    FENCE;                                                                     \
    asm volatile("s_waitcnt vmcnt(0)" ::: "memory");                           \
    __builtin_amdgcn_s_barrier();                                              \
    FENCE;                                                                     \
    if ((kt) + 1 < KT_N) READF(ANXT, BNXT, cbn);                               \
    FENCE;                          /* reads pinned above MFMAs */             \
    if ((kt) + 2 < KT_N) STAGE(cbt, (kt) + 2);                                 \
    FENCE;                          /* stage pinned above MFMAs */             \
    __builtin_amdgcn_s_setprio(1);                                             \
    MFMAS(ACUR, BCUR);                                                         \
    __builtin_amdgcn_s_setprio(0);                                             \
} while (0)

    // prologue: stage tiles 0,1 -> bufs 0,1; counted drain of stage(0);
    // barrier publishes; read tile-0 frags into set X.
    STAGE(0, 0);
    STAGE(1, 1);
    FENCE;
    asm volatile("s_waitcnt vmcnt(6)" ::: "memory");   // stage(0) done, (1) flying
    __builtin_amdgcn_s_barrier();
    FENCE;
    READF(aX, bX, 0);

    int c0 = 0, c1 = 1, c2 = 2;     // cur, next, stage-target buffers
    for (int kt = 0; kt < KT_N; kt += 2) {
        BODY(kt,     aX, bX, aY, bY, c1, c2);
        BODY(kt + 1, aY, bY, aX, bX, c2, c0);
        int t = c0; c0 = c2; c2 = c1; c1 = t;   // advance by 2 tiles
    }

    // epilogue: D col=lane&15 (N), row=(lane>>4)*4+r (M)  [m89-verified]
    // BN=128 divides HDIM -> whole block routes to one output buffer.
    // ai-outer / j-inner (r9 lesson: j-outer caused 3.7x write amplification)
    int n0 = bn * BN;
    float* outp = (n0 < HDIM) ? pc : (n0 < 2 * HDIM) ? pa : ph;
    int nb = n0 & (HDIM - 1);
#pragma unroll
    for (int i = 0; i < 4; ++i)
#pragma unroll
        for (int r = 0; r < 4; ++r) {
            int m = bm * BM + wr * 64 + i * 16 + (lane >> 4) * 4 + r;
#pragma unroll
            for (int j = 0; j < 4; ++j) {
                int n = nb + wc * 64 + j * 16 + (lane & 15);
                outp[(size_t)m * HDIM + n] = acc[i][j][r];
            }
        }
#undef STAGE
#undef READF
#undef MFMAS
#undef BODY
#undef FENCE
}

// ------------------------- recurrence ------------------------------------
// one thread per (b,j); 65536 threads; depth-16 register prefetch pipeline
// (PF=16: 48 outstanding loads <= 63 vmcnt capacity; PF=32 exceeded it).
// libm transcendentals (r8 measured: fast variants null — BW/latency-bound).
__global__ __launch_bounds__(256) void recur(const float* __restrict__ pc_a,
                                             const float* __restrict__ pa_a,
                                             float* out,
                                             const float* __restrict__ h0,
                                             const float* __restrict__ wc_,
                                             const float* __restrict__ bc_,
                                             const float* __restrict__ wa_,
                                             const float* __restrict__ ba_,
                                             const float* __restrict__ bh_) {
    int idx = blockIdx.x * 256 + threadIdx.x;
    int j = idx & (HDIM - 1);
    float h  = h0[idx];
    float wc = wc_[j], bc = bc_[j];
    float wa = wa_[j], ba = ba_[j];
    float bh = bh_[j];

#define PF 16
    float pc[PF], pa[PF], ph[PF];
#pragma unroll
    for (int u = 0; u < PF; ++u) {
        pc[u] = pc_a[(size_t)u * STRIDE + idx];
        pa[u] = pa_a[(size_t)u * STRIDE + idx];
        ph[u] = out [(size_t)u * STRIDE + idx];
    }

    for (int sb = 0; sb < SEQLEN; sb += PF) {
#pragma unroll
        for (int u = 0; u < PF; ++u) {
            int s = sb + u;
            float vc = pc[u], va = pa[u], vh = ph[u];
            int sp = s + PF; sp = (sp < SEQLEN) ? sp : (SEQLEN - 1);
            pc[u] = pc_a[(size_t)sp * STRIDE + idx];
            pa[u] = pa_a[(size_t)sp * STRIDE + idx];
            ph[u] = out [(size_t)sp * STRIDE + idx];

            float zc = (vc + bc) + wc * h;
            float za = (va + ba) + wa * h;
            float c  = 1.0f / (1.0f + expf(-zc));
            float a  = 1.0f + tanhf(za);
            float ht = tanhf((vh + bh) + a * h);
            h = c * h + (1.0f - c) * ht;
            out[(size_t)s * STRIDE + idx] = h;
        }
    }
    out[(size_t)SEQLEN * STRIDE + idx] = h;   // hn
}

// --------------------------- launch --------------------------------------
extern "C" void kernel_launch(void* const* d_in, const int* in_sizes, int n_in,
                              void* d_out, int out_size, void* d_ws, size_t ws_size,
                              hipStream_t stream) {
    const float* x_seq = (const float*)d_in[0];
    const float* h0    = (const float*)d_in[1];
    const float* U_c   = (const float*)d_in[2];
    const float* w_c   = (const float*)d_in[3];
    const float* b_c   = (const float*)d_in[4];
    const float* U_a   = (const float*)d_in[5];
    const float* w_a   = (const float*)d_in[6];
    const float* b_a   = (const float*)d_in[7];
    const float* U_h   = (const float*)d_in[8];
    const float* b_h   = (const float*)d_in[9];
    float* out = (float*)d_out;

    char* ws = (char*)d_ws;
    const size_t MB = 1024 * 1024;
    float*    ws_pc = (float*)ws;                        // 128 MB
    float*    ws_pa = (float*)(ws + 128 * MB);           // 128 MB
    _Float16* x_hi  = (_Float16*)(ws + 256 * MB);        // 32 MB
    _Float16* x_lo  = (_Float16*)(ws + 288 * MB);        // 32 MB
    _Float16* u_hi  = (_Float16*)(ws + 320 * MB);        // 3 MB
    _Float16* u_lo  = (_Float16*)(ws + 323 * MB);        // 3 MB

    cvt_all<<<dim3((XTHREADS + UTHREADS) / 256), dim3(256), 0, stream>>>(
        x_seq, U_c, U_a, U_h, x_hi, x_lo, u_hi, u_lo);
    gemm_f16x2<<<dim3(GRID), dim3(512), 0, stream>>>(
        x_hi, x_lo, u_hi, u_lo, ws_pc, ws_pa, out);
    recur<<<dim3(STRIDE / 256), dim3(256), 0, stream>>>(ws_pc, ws_pa, out, h0,
                                                        w_c, b_c, w_a, b_a, b_h);
}